// Round 6
// baseline (1746.376 us; speedup 1.0000x reference)
//
#include <hip/hip_runtime.h>
#include <hip/hip_bf16.h>
#include <stdint.h>

typedef __bf16 bf16_t;
typedef __bf16 bf16x4 __attribute__((ext_vector_type(4)));
typedef __bf16 bf16x8 __attribute__((ext_vector_type(8)));
typedef float f32x16 __attribute__((ext_vector_type(16)));

#define LDS_CAST(p) ((__attribute__((address_space(3))) void*)(p))
#define GLB_CAST(p) ((const __attribute__((address_space(1))) void*)(p))

__device__ __forceinline__ void gl_lds16(const void* g, void* l) {
  __builtin_amdgcn_global_load_lds(GLB_CAST(g), LDS_CAST(l), 16, 0, 0);
}

#define MFMA32(a,b,c) __builtin_amdgcn_mfma_f32_32x32x16_bf16((a),(b),(c),0,0,0)
#define BARRIER() __builtin_amdgcn_s_barrier()

template<int N> __device__ __forceinline__ void vmw() {
  if constexpr (N == 8)      asm volatile("s_waitcnt vmcnt(8)" ::: "memory");
  else if constexpr (N == 6) asm volatile("s_waitcnt vmcnt(6)" ::: "memory");
  else if constexpr (N == 4) asm volatile("s_waitcnt vmcnt(4)" ::: "memory");
  else if constexpr (N == 0) asm volatile("s_waitcnt vmcnt(0)" ::: "memory");
  // N == -1: no wait
}

static constexpr int M_TOT = 4096, H_DIM = 4096, I_DIM = 14336;

// ---------------------------------------------------------------------------
// fp32 -> bf16 conversion (float4 in, bf16x4 out), grid-stride
// ---------------------------------------------------------------------------
__global__ __launch_bounds__(256)
void k_conv(const float4* __restrict__ src, bf16x4* __restrict__ dst, long n4)
{
  long stride = (long)gridDim.x * blockDim.x;
  for (long i = (long)blockIdx.x * blockDim.x + threadIdx.x; i < n4; i += stride) {
    float4 v = src[i];
    bf16x4 o;
    o[0] = (bf16_t)v.x; o[1] = (bf16_t)v.y; o[2] = (bf16_t)v.z; o[3] = (bf16_t)v.w;
    dst[i] = o;
  }
}

// ===========================================================================
// LDS granule layout (per 32-row x 32-k operand chunk, BK=32):
//   granule g = (rowgrp*2 + kf), 1 KiB each: [hi(2)][row(32)][16B]
//   byte (l>>5)*512 + (l&31)*16  <=>  element [row=l&31][k=kf*16+(l>>5)*8+j]
// Fragment read for mfma_32x32x16: lane l reads granule byte l*16 -> stride-1
// ds_read_b128, conflict-free by construction. Staged via global_load_lds
// with the granule permutation folded into the per-lane GLOBAL source addr.
// ===========================================================================

// GEMM1: A[M,I] = silu(X Wg^T) * (X Wu^T). BM=256, BN=128(G)+128(U), BK=32.
// 8 waves (2M x 4N); 16 x mfma_32x32x16 per K-tile per wave.
// 4 LDS bufs x 32 KiB (X 16K | G 8K | U 8K), lead-3, vmcnt(6)/tile.
__global__ __launch_bounds__(512, 2)
void k_gateup8(const bf16_t* __restrict__ X, const bf16_t* __restrict__ Wg,
               const bf16_t* __restrict__ Wu, bf16_t* __restrict__ Aout)
{
  __shared__ __align__(1024) char lds[131072];
  const int tid = threadIdx.x, wave = tid >> 6, lane = tid & 63;
  const int l31 = lane & 31, hi = lane >> 5;
  const int wm = wave >> 2, wn = wave & 3;
  const int lb = lane * 16;

  // tn-major XCD mapping (16 consecutive blocks per XCD share one tn)
  const int bid = blockIdx.x;                 // grid = 1792
  const int bq  = bid >> 3;                   // 0..223
  const int tn  = (bid & 7) * 14 + (bq >> 4); // 0..111
  const int tm  = bq & 15;                    // 0..15

  // staging source: this wave fills granule g=wave (and g=8+wave for X)
  const int srg = wave >> 1;                  // rowgrp 0..3
  const int skol = (wave & 1) * 16 + hi * 8;  // k element offset in tile
  const int srow = srg * 32 + l31;

  const bf16_t* gX1 = X  + (size_t)(tm * 256 + srow) * H_DIM + skol;
  const bf16_t* gX2 = gX1 + (size_t)128 * H_DIM;
  const bf16_t* gG  = Wg + (size_t)(tn * 128 + srow) * H_DIM + skol;
  const bf16_t* gU  = Wu + (size_t)(tn * 128 + srow) * H_DIM + skol;

  f32x16 accg[4], accu[4];
#pragma unroll
  for (int m = 0; m < 4; ++m)
#pragma unroll
    for (int r = 0; r < 16; ++r) { accg[m][r] = 0.f; accu[m][r] = 0.f; }

  // prologue: stage tiles 0..2
#pragma unroll
  for (int t = 0; t < 3; ++t) {
    char* sb = lds + t * 32768 + wave * 1024;
    gl_lds16(gX1 + t * 32, sb);
    gl_lds16(gX2 + t * 32, sb + 8192);
    gl_lds16(gG  + t * 32, sb + 16384);
    gl_lds16(gU  + t * 32, sb + 24576);
  }
  vmw<8>(); BARRIER();

#define G1_TILE(T, DO_STG, WAITN, DO_BAR)                                    \
  {                                                                          \
    const char* bb = lds + (((T) & 3) << 15);                                \
    if (DO_STG) {                                                            \
      char* sb = lds + ((((T) + 3) & 3) << 15) + wave * 1024;                \
      const int kc = ((T) + 3) * 32;                                         \
      gl_lds16(gX1 + kc, sb);                                                \
      gl_lds16(gX2 + kc, sb + 8192);                                         \
      gl_lds16(gG  + kc, sb + 16384);                                        \
      gl_lds16(gU  + kc, sb + 24576);                                        \
    }                                                                        \
    bf16x8 a[4][2], bgv[2], buv[2];                                          \
    _Pragma("unroll") for (int kf = 0; kf < 2; ++kf) {                       \
      bgv[kf] = *(const bf16x8*)(bb + 16384 + (wn * 2 + kf) * 1024 + lb);    \
      buv[kf] = *(const bf16x8*)(bb + 24576 + (wn * 2 + kf) * 1024 + lb); }  \
    _Pragma("unroll") for (int m = 0; m < 4; ++m)                            \
    _Pragma("unroll") for (int kf = 0; kf < 2; ++kf)                         \
      a[m][kf] = *(const bf16x8*)(bb + ((wm * 4 + m) * 2 + kf) * 1024 + lb); \
    __builtin_amdgcn_s_setprio(1);                                           \
    _Pragma("unroll") for (int m = 0; m < 4; ++m) {                          \
      accg[m] = MFMA32(a[m][0], bgv[0], accg[m]);                            \
      accg[m] = MFMA32(a[m][1], bgv[1], accg[m]);                            \
      accu[m] = MFMA32(a[m][0], buv[0], accu[m]);                            \
      accu[m] = MFMA32(a[m][1], buv[1], accu[m]); }                          \
    __builtin_amdgcn_s_setprio(0);                                           \
    vmw<WAITN>();                                                            \
    if (DO_BAR) BARRIER();                                                   \
  }

  const int NT = H_DIM / 32;                  // 128
  for (int T = 0; T <= NT - 4; ++T)
    G1_TILE(T, true, 6, true);
  G1_TILE(NT - 3, false, 4, true);
  G1_TILE(NT - 2, false, 0, true);
  G1_TILE(NT - 1, false, -1, false);
#undef G1_TILE

  // C/D (32x32): col = lane&31, row = (r&3) + 8*(r>>2) + 4*(lane>>5)
  const int r0 = tm * 256 + wm * 128 + 4 * hi;
  const int c0 = tn * 128 + wn * 32 + l31;
#pragma unroll
  for (int m = 0; m < 4; ++m)
#pragma unroll
    for (int r = 0; r < 16; ++r) {
      const int row = r0 + m * 32 + (r & 3) + 8 * (r >> 2);
      float g = accg[m][r];
      float u = accu[m][r];
      float s = g / (1.0f + __expf(-g));
      Aout[(size_t)row * I_DIM + c0] = (bf16_t)(s * u);
    }
}

// ===========================================================================
// GEMM2: D[M,H] = A Wd^T. BM=BN=256, BK=32, K=I_DIM. Per-wave 128x64.
// 4 bufs x 32 KiB (A 16K | B 16K), same skeleton, 16 x mfma_32x32x16/tile.
// ===========================================================================
__global__ __launch_bounds__(512, 2)
void k_down8(const bf16_t* __restrict__ Aa, const bf16_t* __restrict__ Wd,
             float* __restrict__ D)
{
  __shared__ __align__(1024) char lds[131072];
  const int tid = threadIdx.x, wave = tid >> 6, lane = tid & 63;
  const int l31 = lane & 31, hi = lane >> 5;
  const int wm = wave >> 2, wn = wave & 3;
  const int lb = lane * 16;

  const int bid = blockIdx.x;                 // grid = 256
  const int bq  = bid >> 3;                   // 0..31
  const int tn  = (bid & 7) * 2 + (bq >> 4);  // 0..15
  const int tm  = bq & 15;                    // 0..15

  const int srg = wave >> 1;
  const int skol = (wave & 1) * 16 + hi * 8;
  const int srow = srg * 32 + l31;

  const bf16_t* gA1 = Aa + (size_t)(tm * 256 + srow) * I_DIM + skol;
  const bf16_t* gA2 = gA1 + (size_t)128 * I_DIM;
  const bf16_t* gB1 = Wd + (size_t)(tn * 256 + srow) * I_DIM + skol;
  const bf16_t* gB2 = gB1 + (size_t)128 * I_DIM;

  f32x16 acc[4][2];
#pragma unroll
  for (int m = 0; m < 4; ++m)
#pragma unroll
    for (int n = 0; n < 2; ++n)
#pragma unroll
      for (int r = 0; r < 16; ++r) acc[m][n][r] = 0.f;

#pragma unroll
  for (int t = 0; t < 3; ++t) {
    char* sb = lds + t * 32768 + wave * 1024;
    gl_lds16(gA1 + t * 32, sb);
    gl_lds16(gA2 + t * 32, sb + 8192);
    gl_lds16(gB1 + t * 32, sb + 16384);
    gl_lds16(gB2 + t * 32, sb + 24576);
  }
  vmw<8>(); BARRIER();

#define G2_TILE(T, DO_STG, WAITN, DO_BAR)                                    \
  {                                                                          \
    const char* bb = lds + (((T) & 3) << 15);                                \
    if (DO_STG) {                                                            \
      char* sb = lds + ((((T) + 3) & 3) << 15) + wave * 1024;                \
      const int kc = ((T) + 3) * 32;                                         \
      gl_lds16(gA1 + kc, sb);                                                \
      gl_lds16(gA2 + kc, sb + 8192);                                         \
      gl_lds16(gB1 + kc, sb + 16384);                                        \
      gl_lds16(gB2 + kc, sb + 24576);                                        \
    }                                                                        \
    bf16x8 a[4][2], bv[2][2];                                                \
    _Pragma("unroll") for (int n = 0; n < 2; ++n)                            \
    _Pragma("unroll") for (int kf = 0; kf < 2; ++kf)                         \
      bv[n][kf] = *(const bf16x8*)(bb + 16384 +                              \
                    ((wn * 2 + n) * 2 + kf) * 1024 + lb);                    \
    _Pragma("unroll") for (int m = 0; m < 4; ++m)                            \
    _Pragma("unroll") for (int kf = 0; kf < 2; ++kf)                         \
      a[m][kf] = *(const bf16x8*)(bb + ((wm * 4 + m) * 2 + kf) * 1024 + lb); \
    __builtin_amdgcn_s_setprio(1);                                           \
    _Pragma("unroll") for (int m = 0; m < 4; ++m)                            \
    _Pragma("unroll") for (int n = 0; n < 2; ++n) {                          \
      acc[m][n] = MFMA32(a[m][0], bv[n][0], acc[m][n]);                      \
      acc[m][n] = MFMA32(a[m][1], bv[n][1], acc[m][n]); }                    \
    __builtin_amdgcn_s_setprio(0);                                           \
    vmw<WAITN>();                                                            \
    if (DO_BAR) BARRIER();                                                   \
  }

  const int NT = I_DIM / 32;                  // 448
  for (int T = 0; T <= NT - 4; ++T)
    G2_TILE(T, true, 6, true);
  G2_TILE(NT - 3, false, 4, true);
  G2_TILE(NT - 2, false, 0, true);
  G2_TILE(NT - 1, false, -1, false);
#undef G2_TILE

  const int r0 = tm * 256 + wm * 128 + 4 * hi;
  const int c0 = tn * 256 + wn * 64 + l31;
#pragma unroll
  for (int m = 0; m < 4; ++m)
#pragma unroll
    for (int n = 0; n < 2; ++n)
#pragma unroll
      for (int r = 0; r < 16; ++r) {
        const int row = r0 + m * 32 + (r & 3) + 8 * (r >> 2);
        D[(size_t)row * H_DIM + c0 + n * 32] = acc[m][n][r];
      }
}

// ---------------------------------------------------------------------------
extern "C" void kernel_launch(void* const* d_in, const int* in_sizes, int n_in,
                              void* d_out, int out_size, void* d_ws, size_t ws_size,
                              hipStream_t stream) {
  const float* x  = (const float*)d_in[0];
  const float* wg = (const float*)d_in[1];
  const float* wu = (const float*)d_in[2];
  const float* wd = (const float*)d_in[3];
  float* out = (float*)d_out;

  const size_t A_BYTES = (size_t)M_TOT * I_DIM * 2;
  const size_t X_BYTES = (size_t)M_TOT * H_DIM * 2;
  const size_t W_BYTES = (size_t)I_DIM * H_DIM * 2;
  char* ws = (char*)d_ws;
  bf16_t* Ab  = (bf16_t*)(ws);
  bf16_t* Xb  = (bf16_t*)(ws + A_BYTES);
  bf16_t* Wgb = (bf16_t*)(ws + A_BYTES + X_BYTES);
  bf16_t* Wub = (bf16_t*)(ws + A_BYTES + X_BYTES + W_BYTES);
  bf16_t* Wdb = Wgb;   // reuse after k_gateup8 consumed Wgb

  const long nX = (long)M_TOT * H_DIM / 4;
  const long nW = (long)I_DIM * H_DIM / 4;

  k_conv<<<dim3(2048), dim3(256), 0, stream>>>((const float4*)x,  (bf16x4*)Xb,  nX);
  k_conv<<<dim3(2048), dim3(256), 0, stream>>>((const float4*)wg, (bf16x4*)Wgb, nW);
  k_conv<<<dim3(2048), dim3(256), 0, stream>>>((const float4*)wu, (bf16x4*)Wub, nW);

  k_gateup8<<<dim3(16 * 112), dim3(512), 0, stream>>>(Xb, Wgb, Wub, Ab);

  k_conv<<<dim3(2048), dim3(256), 0, stream>>>((const float4*)wd, (bf16x4*)Wdb, nW);

  k_down8<<<dim3(16 * 16), dim3(512), 0, stream>>>(Ab, Wdb, out);
}